// Round 10
// baseline (299.233 us; speedup 1.0000x reference)
//
#include <hip/hip_runtime.h>
#include <math.h>

#define DIM      4096
#define KSEL     2048
#define NTHREADS 256
#define VPT      16            // DIM / NTHREADS
#define RPB      8             // rows per block (grid-stride pipeline depth)
#define LO_BITS  0x3D800000u   // 0.0625  — threshold search window lo
#define HI_BITS  0x3F800000u   // 1.0     — threshold search window hi
#define BSHIFT   17            // (HI-LO)>>17 == 256 buckets
#define CAP      256           // candidate list capacity

typedef float vfloat4 __attribute__((ext_vector_type(4)));

// ---- bit-exact XLA-CPU silu: s = 1/(1+cephes_exp_fma(-x)); h = x*s ----
// Verified absmax == 0.0 in round 4. DO NOT MODIFY.
__device__ __forceinline__ float cephes_expf_fma(float x) {
    const float LOG2EF = 1.44269504088896341f;
    const float C1     = 0.693359375f;
    const float C2     = -2.12194440e-4f;
    float z0 = __builtin_fmaf(x, LOG2EF, 0.5f);
    float fx = floorf(z0);
    float r  = __fsub_rn(x, __fmul_rn(fx, C1));
    r = __builtin_fmaf(fx, -C2, r);
    float zz = __fmul_rn(r, r);
    float y  = 1.9875691500e-4f;
    y = __builtin_fmaf(y, r, 1.3981999507e-3f);
    y = __builtin_fmaf(y, r, 8.3334519073e-3f);
    y = __builtin_fmaf(y, r, 4.1665795894e-2f);
    y = __builtin_fmaf(y, r, 1.6666665459e-1f);
    y = __builtin_fmaf(y, r, 5.0000001201e-1f);
    y = __builtin_fmaf(y, zz, r);
    y = __fadd_rn(y, 1.0f);
    int n = (int)fx;
    float scale = __int_as_float((n + 127) << 23);
    return __fmul_rn(y, scale);
}

__device__ __forceinline__ float silu_ref(float x) {
    float e = cephes_expf_fma(-x);
    float s = __fdiv_rn(1.0f, __fadd_rn(1.0f, e));
    return __fmul_rn(x, s);
}

__global__ __launch_bounds__(NTHREADS, 6) void topk_silu_kernel(
    const float* __restrict__ x, float* __restrict__ out)
{
    const int tid  = threadIdx.x;
    const int lane = tid & 63;
    const int wave = tid >> 6;

    const size_t row0 = (size_t)blockIdx.x * RPB;

    __shared__ int      hist[256];
    __shared__ int      wred[4];
    __shared__ int      wscan[4];
    __shared__ unsigned s_dig;
    __shared__ int      s_krem;
    __shared__ int      s_nb;
    __shared__ int      s_found;
    __shared__ unsigned s_thr;
    __shared__ int      s_cnt;
    __shared__ unsigned list[CAP];

    // invariant at each row's B1: hist all-zero, s_found=0, s_cnt=0, s_thr=~0
    hist[tid] = 0;
    if (tid == 0) { s_found = 0; s_cnt = 0; s_thr = 0xFFFFFFFFu; }

    // prime the pipeline: row 0 into registers
    float4 xc[4], xn[4];
    {
        const float4* __restrict__ xp =
            reinterpret_cast<const float4*>(x + row0 * DIM);
        #pragma unroll
        for (int j = 0; j < 4; ++j) xc[j] = xp[j * NTHREADS + tid];
    }

    #pragma unroll 1
    for (int r = 0; r < RPB; ++r) {
        // ---- issue next row's loads first: in flight during silu+select ----
        if (r + 1 < RPB) {
            const float4* __restrict__ xq =
                reinterpret_cast<const float4*>(x + (row0 + r + 1) * DIM);
            #pragma unroll
            for (int j = 0; j < 4; ++j) xn[j] = xq[j * NTHREADS + tid];
        }

        // ---- bit-exact f32 silu; hb = h bit patterns ----
        unsigned hb[VPT];
        #pragma unroll
        for (int j = 0; j < 4; ++j) {
            const float* vp = &xc[j].x;
            #pragma unroll
            for (int c4 = 0; c4 < 4; ++c4)
                hb[j*4+c4] = __float_as_uint(silu_ref(vp[c4]));
        }
        __syncthreads();                                   // B1

        // ---- bucket pass over threshold window + above-window count ----
        int nhi = 0;
        #pragma unroll
        for (int q = 0; q < VPT; ++q) {
            unsigned k  = hb[q] & 0x7FFFFFFFu;
            nhi += (k >= HI_BITS) ? 1 : 0;
            unsigned bk = (k - LO_BITS) >> BSHIFT;         // wraps huge if k < LO
            if (bk < 256u) atomicAdd(&hist[bk], 1);
        }
        #pragma unroll
        for (int off = 32; off; off >>= 1) nhi += __shfl_xor(nhi, off);
        if (lane == 0) wred[wave] = nhi;
        __syncthreads();                                   // B2
        const int n_hi = wred[0] + wred[1] + wred[2] + wred[3];

        int c = hist[tid];
        hist[tid] = 0;                                     // zero-after-read
        int s = c;
        #pragma unroll
        for (int off = 1; off < 64; off <<= 1) {
            int t = __shfl_down(s, off);
            if (lane + off < 64) s += t;
        }
        if (lane == 0) wscan[wave] = s;
        __syncthreads();                                   // B3
        #pragma unroll
        for (int w = 0; w < 4; ++w)
            if (w > wave) s += wscan[w];
        s += n_hi;

        if (s >= KSEL && s - c < KSEL) {                   // K-th in this bucket
            s_dig   = (unsigned)tid;
            s_krem  = KSEL - (s - c);
            s_nb    = c;
            s_found = 1;
        }
        __syncthreads();                                   // B4

        unsigned thr_bits;
        if (s_found && s_nb <= CAP) {
            // ---- fast path: exact rank among few bucket candidates ----
            const unsigned bsel = s_dig;
            const int      krem = s_krem;
            const int      nb   = s_nb;
            #pragma unroll
            for (int q = 0; q < VPT; ++q) {
                unsigned k = hb[q] & 0x7FFFFFFFu;
                if (((k - LO_BITS) >> BSHIFT) == bsel) {
                    int idx = atomicAdd(&s_cnt, 1);
                    list[idx] = k;
                }
            }
            __syncthreads();                               // B5
            if (tid < nb) {
                unsigned ki = list[tid];
                int rk = 0;
                for (int j = 0; j < nb; ++j) rk += (list[j] > ki) ? 1 : 0;
                if (rk < krem) atomicMin(&s_thr, ki);
            }
            __syncthreads();                               // B6
            thr_bits = s_thr;
        } else {
            // ---- fallback: full 4-pass radix select (distribution-free) ----
            // entry invariant: hist all-zero
            unsigned prefix = 0;
            int      krem   = KSEL;
            #pragma unroll 1
            for (int pass = 0; pass < 4; ++pass) {
                const int shift = 24 - pass * 8;
                const unsigned himask =
                    (pass == 0) ? 0u : (0xFFFFFFFFu << (shift + 8));
                #pragma unroll
                for (int q = 0; q < VPT; ++q) {
                    unsigned k = hb[q] & 0x7FFFFFFFu;
                    if ((k & himask) == prefix)
                        atomicAdd(&hist[(k >> shift) & 255u], 1);
                }
                __syncthreads();
                c = hist[tid];
                hist[tid] = 0;                             // keep invariant
                s = c;
                #pragma unroll
                for (int off = 1; off < 64; off <<= 1) {
                    int t = __shfl_down(s, off);
                    if (lane + off < 64) s += t;
                }
                if (lane == 0) wscan[wave] = s;
                __syncthreads();
                #pragma unroll
                for (int w = 0; w < 4; ++w)
                    if (w > wave) s += wscan[w];
                if (s >= krem && s - c < krem) {
                    s_dig  = (unsigned)tid;
                    s_krem = krem - (s - c);
                }
                __syncthreads();
                prefix |= s_dig << shift;
                krem    = s_krem;
            }
            thr_bits = prefix;
        }

        // ---- write: keep iff |h| >= thr; non-temporal (never re-read) ----
        vfloat4* __restrict__ oq =
            reinterpret_cast<vfloat4*>(out + (row0 + r) * DIM);
        #pragma unroll
        for (int j = 0; j < 4; ++j) {
            vfloat4 o;
            #pragma unroll
            for (int c4 = 0; c4 < 4; ++c4) {
                unsigned h = hb[j*4+c4];
                o[c4] = ((h & 0x7FFFFFFFu) >= thr_bits)
                            ? __uint_as_float(h) : 0.0f;
            }
            __builtin_nontemporal_store(o, &oq[j * NTHREADS + tid]);
        }

        if (r + 1 < RPB) {
            __syncthreads();                               // B7: quiesce row
            if (tid == 0) { s_found = 0; s_cnt = 0; s_thr = 0xFFFFFFFFu; }
            #pragma unroll
            for (int j = 0; j < 4; ++j) xc[j] = xn[j];
        }
    }
}

extern "C" void kernel_launch(void* const* d_in, const int* in_sizes, int n_in,
                              void* d_out, int out_size, void* d_ws, size_t ws_size,
                              hipStream_t stream) {
    const float* x   = (const float*)d_in[0];
    float*       out = (float*)d_out;
    const int rows = in_sizes[0] / DIM;   // 4 * 4096 = 16384
    topk_silu_kernel<<<rows / RPB, NTHREADS, 0, stream>>>(x, out);
}

// Round 11
// 185.915 us; speedup vs baseline: 1.6095x; 1.6095x over previous
//
#include <hip/hip_runtime.h>
#include <math.h>

#define DIM      4096
#define KSEL     2048
#define NTHREADS 256
#define WPB      4             // waves per block = rows per block
#define EPL      64            // elements per lane (DIM / 64)
#define NQ       16            // float4 loads per lane
#define MBITS    0x7FFFFFFFu
#define LO_BITS  0x3D800000u   // 0.0625 — data-informed first window lo
#define HI_BITS  0x3F800000u   // 1.0    — data-informed first window hi
#define CAP      64            // candidate list capacity (one per lane)

// ---- bit-exact XLA-CPU silu: s = 1/(1+cephes_exp_fma(-x)); h = x*s ----
// Verified absmax == 0.0 in round 4. DO NOT MODIFY.
__device__ __forceinline__ float cephes_expf_fma(float x) {
    const float LOG2EF = 1.44269504088896341f;
    const float C1     = 0.693359375f;
    const float C2     = -2.12194440e-4f;
    float z0 = __builtin_fmaf(x, LOG2EF, 0.5f);
    float fx = floorf(z0);
    float r  = __fsub_rn(x, __fmul_rn(fx, C1));
    r = __builtin_fmaf(fx, -C2, r);
    float zz = __fmul_rn(r, r);
    float y  = 1.9875691500e-4f;
    y = __builtin_fmaf(y, r, 1.3981999507e-3f);
    y = __builtin_fmaf(y, r, 8.3334519073e-3f);
    y = __builtin_fmaf(y, r, 4.1665795894e-2f);
    y = __builtin_fmaf(y, r, 1.6666665459e-1f);
    y = __builtin_fmaf(y, r, 5.0000001201e-1f);
    y = __builtin_fmaf(y, zz, r);
    y = __fadd_rn(y, 1.0f);
    int n = (int)fx;
    float scale = __int_as_float((n + 127) << 23);
    return __fmul_rn(y, scale);
}

__device__ __forceinline__ float silu_ref(float x) {
    float e = cephes_expf_fma(-x);
    float s = __fdiv_rn(1.0f, __fadd_rn(1.0f, e));
    return __fmul_rn(x, s);
}

// wave-internal ordering fence: drain this wave's LDS ops; no cross-wave wait
__device__ __forceinline__ void wave_sync() {
    asm volatile("s_waitcnt lgkmcnt(0)" ::: "memory");
    __builtin_amdgcn_wave_barrier();
}

__global__ __launch_bounds__(NTHREADS, 4) void topk_silu_kernel(
    const float* __restrict__ x, float* __restrict__ out)
{
    const int tid  = threadIdx.x;
    const int lane = tid & 63;
    const int wave = tid >> 6;

    const size_t row = (size_t)blockIdx.x * WPB + wave;
    const float4* __restrict__ xr4 =
        reinterpret_cast<const float4*>(x + row * DIM);
    float4* __restrict__ or4 =
        reinterpret_cast<float4*>(out + row * DIM);

    __shared__ int      hist_s[WPB][256];
    __shared__ unsigned list_s[WPB][CAP];
    __shared__ int      cnt_s[WPB];
    int*      const hist = hist_s[wave];
    unsigned* const list = list_s[wave];

    // ---- load + bit-exact silu; hb in registers (static indexing only) ----
    unsigned hb[EPL];
    int nhi = 0, nwin = 0;
    #pragma unroll
    for (int j = 0; j < NQ; ++j) {
        float4 v = xr4[j * 64 + lane];
        const float* vp = &v.x;
        #pragma unroll
        for (int c4 = 0; c4 < 4; ++c4) {
            unsigned h = __float_as_uint(silu_ref(vp[c4]));
            hb[j*4+c4] = h;
            unsigned k = h & MBITS;
            nhi  += (k >= HI_BITS) ? 1 : 0;
            nwin += (k >= LO_BITS && k < HI_BITS) ? 1 : 0;
        }
    }
    #pragma unroll
    for (int off = 32; off; off >>= 1) {
        nhi  += __shfl_xor(nhi,  off);
        nwin += __shfl_xor(nwin, off);
    }

    // ---- window init (wave-uniform after reduce) ----
    unsigned wlo;
    int      bshift, krem;
    if (KSEL <= nhi)               { wlo = HI_BITS; bshift = 23; krem = KSEL; }
    else if (KSEL <= nhi + nwin)   { wlo = LO_BITS; bshift = 17; krem = KSEL - nhi; }
    else                           { wlo = 0u;      bshift = 22; krem = KSEL - nhi - nwin; }

    // ---- bucket-refinement select, fully wave-local (no __syncthreads) ----
    unsigned thr;
    for (;;) {
        wave_sync();
        hist[lane]       = 0;
        hist[lane + 64]  = 0;
        hist[lane + 128] = 0;
        hist[lane + 192] = 0;
        wave_sync();

        #pragma unroll
        for (int e = 0; e < EPL; ++e) {
            unsigned d = (hb[e] & MBITS) - wlo;     // wraps huge if below window
            unsigned b = d >> bshift;
            if (b < 256u) atomicAdd(&hist[b], 1);
        }
        wave_sync();

        const int c0 = hist[lane*4+0];
        const int c1 = hist[lane*4+1];
        const int c2 = hist[lane*4+2];
        const int c3 = hist[lane*4+3];
        const int lsum = c0 + c1 + c2 + c3;

        // inclusive suffix over lanes (sum of lsum for lanes >= this one)
        int s = lsum;
        #pragma unroll
        for (int off = 1; off < 64; off <<= 1) {
            int t = __shfl_down(s, off);
            if (lane + off < 64) s += t;
        }
        const int shigher = s - lsum;     // lanes strictly above
        const int s3 = shigher + c3;
        const int s2 = s3 + c2;
        const int s1 = s2 + c1;
        const int s0 = s1 + c0;

        int fbin = 256, fkrem = 0, fnb = 0;
        if (s0 >= krem && s0 - c0 < krem) { fbin = lane*4+0; fkrem = krem-(s0-c0); fnb = c0; }
        if (s1 >= krem && s1 - c1 < krem) { fbin = lane*4+1; fkrem = krem-(s1-c1); fnb = c1; }
        if (s2 >= krem && s2 - c2 < krem) { fbin = lane*4+2; fkrem = krem-(s2-c2); fnb = c2; }
        if (s3 >= krem && s3 - c3 < krem) { fbin = lane*4+3; fkrem = krem-(s3-c3); fnb = c3; }

        const unsigned long long m = __ballot(fbin < 256);
        const int wl   = __ffsll((long long)m) - 1;
        const int bsel = __shfl(fbin,  wl);
        krem           = __shfl(fkrem, wl);
        const int nb   = __shfl(fnb,   wl);
        wlo += ((unsigned)bsel) << bshift;

        if (nb <= CAP) {
            // exact rank among the few candidates (wave-local)
            if (lane == 0) cnt_s[wave] = 0;
            wave_sync();
            const unsigned width = 1u << bshift;
            #pragma unroll
            for (int e = 0; e < EPL; ++e) {
                unsigned k = hb[e] & MBITS;
                if (k - wlo < width) {          // unsigned wrap handles k < wlo
                    int i = atomicAdd(&cnt_s[wave], 1);
                    list[i] = k;
                }
            }
            wave_sync();
            unsigned cand = 0xFFFFFFFFu;
            if (lane < nb) {
                unsigned ki = list[lane];
                int rk = 0;
                for (int j = 0; j < nb; ++j) rk += (list[j] > ki) ? 1 : 0;
                if (rk < krem) cand = ki;       // ties all kept, like ref
            }
            #pragma unroll
            for (int off = 32; off; off >>= 1) {
                unsigned o = __shfl_xor(cand, off);
                cand = (o < cand) ? o : cand;
            }
            thr = cand;
            break;
        }
        if (bshift == 0) { thr = wlo; break; }  // width-1 bucket: all ties, keep all
        bshift = (bshift > 8) ? (bshift - 8) : 0;
    }

    // ---- write: keep iff |h| >= thr (bit compare) ----
    #pragma unroll
    for (int j = 0; j < NQ; ++j) {
        float4 o;
        float* op = &o.x;
        #pragma unroll
        for (int c4 = 0; c4 < 4; ++c4) {
            unsigned h = hb[j*4+c4];
            op[c4] = ((h & MBITS) >= thr) ? __uint_as_float(h) : 0.0f;
        }
        or4[j * 64 + lane] = o;
    }
}

extern "C" void kernel_launch(void* const* d_in, const int* in_sizes, int n_in,
                              void* d_out, int out_size, void* d_ws, size_t ws_size,
                              hipStream_t stream) {
    const float* x   = (const float*)d_in[0];
    float*       out = (float*)d_out;
    const int rows = in_sizes[0] / DIM;   // 4 * 4096 = 16384
    topk_silu_kernel<<<rows / WPB, NTHREADS, 0, stream>>>(x, out);
}

// Round 12
// 117.326 us; speedup vs baseline: 2.5504x; 1.5846x over previous
//
#include <hip/hip_runtime.h>
#include <math.h>

#define DIM      4096
#define KSEL     2048
#define NTHREADS 256
#define VPT      16            // DIM / NTHREADS
#define LO_BITS  0x3D800000u   // 0.0625 — threshold search window lo
#define HI_BITS  0x3F800000u   // 1.0    — window hi (bin 255 clamps to +inf)
#define BSHIFT   17            // (HI-LO)>>17 == 256 buckets
#define CAP      256           // candidate list capacity

// ---- bit-exact XLA-CPU silu: s = 1/(1+cephes_exp_fma(-x)); h = x*s ----
// Verified absmax == 0.0 in rounds 4-11. DO NOT MODIFY.
__device__ __forceinline__ float cephes_expf_fma(float x) {
    const float LOG2EF = 1.44269504088896341f;
    const float C1     = 0.693359375f;
    const float C2     = -2.12194440e-4f;
    float z0 = __builtin_fmaf(x, LOG2EF, 0.5f);
    float fx = floorf(z0);
    float r  = __fsub_rn(x, __fmul_rn(fx, C1));
    r = __builtin_fmaf(fx, -C2, r);
    float zz = __fmul_rn(r, r);
    float y  = 1.9875691500e-4f;
    y = __builtin_fmaf(y, r, 1.3981999507e-3f);
    y = __builtin_fmaf(y, r, 8.3334519073e-3f);
    y = __builtin_fmaf(y, r, 4.1665795894e-2f);
    y = __builtin_fmaf(y, r, 1.6666665459e-1f);
    y = __builtin_fmaf(y, r, 5.0000001201e-1f);
    y = __builtin_fmaf(y, zz, r);
    y = __fadd_rn(y, 1.0f);
    int n = (int)fx;
    float scale = __int_as_float((n + 127) << 23);
    return __fmul_rn(y, scale);
}

__device__ __forceinline__ float silu_ref(float x) {
    float e = cephes_expf_fma(-x);
    float s = __fdiv_rn(1.0f, __fadd_rn(1.0f, e));
    return __fmul_rn(x, s);
}

__global__ __launch_bounds__(NTHREADS) void topk_silu_kernel(
    const float* __restrict__ x, float* __restrict__ out)
{
    const int tid  = threadIdx.x;
    const int lane = tid & 63;
    const int wave = tid >> 6;

    const float4* __restrict__ xr4 =
        reinterpret_cast<const float4*>(x + (size_t)blockIdx.x * DIM);
    float4* __restrict__ or4 =
        reinterpret_cast<float4*>(out + (size_t)blockIdx.x * DIM);

    __shared__ int      hist[256];
    __shared__ int      wscan[4];
    __shared__ unsigned s_dig;
    __shared__ int      s_krem;
    __shared__ int      s_nb;
    __shared__ int      s_found;
    __shared__ unsigned s_thr;
    __shared__ int      s_cnt;
    __shared__ unsigned list[CAP];

    hist[tid] = 0;
    if (tid == 0) { s_found = 0; s_cnt = 0; s_thr = 0xFFFFFFFFu; }
    __syncthreads();                                       // B0: hist ready

    // ---- fused: load + bit-exact silu + clamped bucket histogram ----
    // bin b<255: [LO + b*2^17, LO + (b+1)*2^17);  bin 255: [LO + 255*2^17, inf)
    unsigned hb[VPT];
    #pragma unroll
    for (int j = 0; j < 4; ++j) {
        float4 v = xr4[j * NTHREADS + tid];
        const float* vp = &v.x;
        #pragma unroll
        for (int c4 = 0; c4 < 4; ++c4) {
            unsigned h = __float_as_uint(silu_ref(vp[c4]));
            hb[j*4+c4] = h;
            unsigned k = h & 0x7FFFFFFFu;
            if (k >= LO_BITS) {
                unsigned bk = (k - LO_BITS) >> BSHIFT;
                if (bk > 255u) bk = 255u;
                atomicAdd(&hist[bk], 1);
            }
        }
    }
    __syncthreads();                                       // B1: hist complete

    // ---- suffix scan over 256 buckets: s = count(keys >= bucket start) ----
    const int c = hist[tid];
    int s = c;
    #pragma unroll
    for (int off = 1; off < 64; off <<= 1) {
        int t = __shfl_down(s, off);
        if (lane + off < 64) s += t;
    }
    if (lane == 0) wscan[wave] = s;
    __syncthreads();                                       // B2
    #pragma unroll
    for (int w = 0; w < 4; ++w)
        if (w > wave) s += wscan[w];

    if (s >= KSEL && s - c < KSEL) {       // K-th largest lands in this bucket
        s_dig   = (unsigned)tid;
        s_krem  = KSEL - (s - c);
        s_nb    = c;
        s_found = 1;
    }
    __syncthreads();                                       // B3

    unsigned thr_bits;
    if (s_found && s_nb <= CAP) {
        // ---- fast path: exact rank among the few bucket candidates ----
        // (if threshold bucket were bin 255, nb >= krem = 2048 > CAP -> fallback)
        const unsigned bsel = s_dig;
        const int      krem = s_krem;
        const int      nb   = s_nb;
        #pragma unroll
        for (int q = 0; q < VPT; ++q) {
            unsigned k = hb[q] & 0x7FFFFFFFu;
            if (k >= LO_BITS) {
                unsigned bk = (k - LO_BITS) >> BSHIFT;
                if (bk > 255u) bk = 255u;
                if (bk == bsel) {
                    int idx = atomicAdd(&s_cnt, 1);
                    list[idx] = k;
                }
            }
        }
        __syncthreads();                                   // B4
        if (tid < nb) {
            unsigned ki = list[tid];
            int rk = 0;
            for (int j = 0; j < nb; ++j) rk += (list[j] > ki) ? 1 : 0;
            if (rk < krem) atomicMin(&s_thr, ki);          // ties all kept
        }
        __syncthreads();                                   // B5
        thr_bits = s_thr;
    } else {
        // ---- fallback: full 4-pass radix select (distribution-free) ----
        unsigned prefix = 0;
        int      krem   = KSEL;
        #pragma unroll 1
        for (int pass = 0; pass < 4; ++pass) {
            const int shift = 24 - pass * 8;
            hist[tid] = 0;
            __syncthreads();
            const unsigned himask =
                (pass == 0) ? 0u : (0xFFFFFFFFu << (shift + 8));
            #pragma unroll
            for (int q = 0; q < VPT; ++q) {
                unsigned k = hb[q] & 0x7FFFFFFFu;
                if ((k & himask) == prefix)
                    atomicAdd(&hist[(k >> shift) & 255u], 1);
            }
            __syncthreads();
            int cc = hist[tid];
            int ss = cc;
            #pragma unroll
            for (int off = 1; off < 64; off <<= 1) {
                int t = __shfl_down(ss, off);
                if (lane + off < 64) ss += t;
            }
            if (lane == 0) wscan[wave] = ss;
            __syncthreads();
            #pragma unroll
            for (int w = 0; w < 4; ++w)
                if (w > wave) ss += wscan[w];
            if (ss >= krem && ss - cc < krem) {
                s_dig  = (unsigned)tid;
                s_krem = krem - (ss - cc);
            }
            __syncthreads();
            prefix |= s_dig << shift;
            krem    = s_krem;
        }
        thr_bits = prefix;
    }

    // ---- write: keep iff |h| >= thr (bit compare; regular stores) ----
    #pragma unroll
    for (int j = 0; j < 4; ++j) {
        float4 o;
        float* op = &o.x;
        #pragma unroll
        for (int c4 = 0; c4 < 4; ++c4) {
            unsigned h = hb[j*4+c4];
            op[c4] = ((h & 0x7FFFFFFFu) >= thr_bits) ? __uint_as_float(h) : 0.0f;
        }
        or4[j * NTHREADS + tid] = o;
    }
}

extern "C" void kernel_launch(void* const* d_in, const int* in_sizes, int n_in,
                              void* d_out, int out_size, void* d_ws, size_t ws_size,
                              hipStream_t stream) {
    const float* x   = (const float*)d_in[0];
    float*       out = (float*)d_out;
    const int rows = in_sizes[0] / DIM;   // 4 * 4096 = 16384
    topk_silu_kernel<<<rows, NTHREADS, 0, stream>>>(x, out);
}